// Round 8
// baseline (2872.083 us; speedup 1.0000x reference)
//
#include <hip/hip_runtime.h>
#include <hip/hip_fp16.h>
#include <stdint.h>

#define TT 1024
#define BB 64
#define DHH 256
#define HH 512
#define G3 1536
#define CHK 256   // f16 elements per (g,jsl) exchange chunk: [16 batches][16 j] — ONE constant, used by store/poll/reader

typedef _Float16 f16;
typedef _Float16 f16x4 __attribute__((ext_vector_type(4)));
typedef _Float16 f16x8 __attribute__((ext_vector_type(8)));
typedef float f32x4 __attribute__((ext_vector_type(4)));
typedef unsigned long long u64;

__device__ __forceinline__ float sigm(float x){ return 1.0f/(1.0f+__expf(-x)); }
__device__ __forceinline__ float tanh_f(float x){ return 2.0f/(1.0f+__expf(-2.0f*x)) - 1.0f; }

// ---------------- prep: f32->f16 weights, folded bias ----------------
__global__ void k_prep(const float* __restrict__ wih, const float* __restrict__ whh,
                       const float* __restrict__ bih, const float* __restrict__ bhh,
                       f16* __restrict__ wih_h, f16* __restrict__ whh_h, float* __restrict__ biasf){
  int i = blockIdx.x*256 + threadIdx.x;
  if (i < G3*HH){ wih_h[i] = (f16)wih[i]; whh_h[i] = (f16)whh[i]; }
  // fold b_ih (all gates) + b_hh (r,z gates only; n-gate's b_hh stays inside r*(...))
  if (i < G3) biasf[i] = bih[i] + (i < 2*HH ? bhh[i] : 0.0f);
}

// ---------------- build x = concat(s, p.sum(axis=2)) as f16 [T*B][512] ----------------
__global__ void k_buildx(const float* __restrict__ s, const float* __restrict__ p, f16* __restrict__ x){
  int m = blockIdx.x;             // m = t*64 + b
  int t = m >> 6, b = m & 63;
  int l = threadIdx.x;            // 0..63 -> 4 floats each
  const float4* s4 = reinterpret_cast<const float4*>(s + ((size_t)b*TT + t)*DHH);
  const float4* p4 = reinterpret_cast<const float4*>(p + ((size_t)b*TT + t)*8*DHH);
  float4 sv = s4[l];
  float4 a  = p4[l];
#pragma unroll
  for (int k=1;k<8;k++){ float4 v = p4[k*64 + l]; a.x+=v.x; a.y+=v.y; a.z+=v.z; a.w+=v.w; }
  f16* xr = x + (size_t)m*HH;
  f16x4 hs = { (f16)sv.x,(f16)sv.y,(f16)sv.z,(f16)sv.w };
  f16x4 hp = { (f16)a.x,(f16)a.y,(f16)a.z,(f16)a.w };
  *reinterpret_cast<f16x4*>(xr + l*4)       = hs;
  *reinterpret_cast<f16x4*>(xr + 256 + l*4) = hp;
}

// ---------------- gi GEMM: D[wrow][xrow] = sum_k W_ih[wrow][k] * x[xrow][k]  (+bias) ----------------
// Writes gi in scan-friendly layout: gi[((t*16+ksl)*4+g)*16 + b'][96] f16, 96 = gate*32 + j'
#define LDAP 72
__global__ __launch_bounds__(256) void k_gemm(const f16* __restrict__ x, const f16* __restrict__ w,
                       const float* __restrict__ biasf, f16* __restrict__ gi){
  __shared__ f16 lA[128*LDAP];   // W tile   [128 wrows][64 k] padded
  __shared__ f16 lB[128*LDAP];   // x tile   [128 xrows][64 k] padded
  int by = blockIdx.x;           // wrow tile (12)
  int bx = blockIdx.y;           // xrow tile (512)
  int tid = threadIdx.x, l = tid & 63, wv = tid >> 6;
  int wm = wv >> 1, wn = wv & 1;

  f32x4 acc[4][4];
#pragma unroll
  for (int i=0;i<4;i++)
#pragma unroll
    for (int j=0;j<4;j++) acc[i][j] = (f32x4){0.f,0.f,0.f,0.f};

  for (int kt = 0; kt < 8; ++kt){
#pragma unroll
    for (int r = 0; r < 4; ++r){
      int c = tid + 256*r;            // 1024 chunks of 16B
      int row = c >> 3, o = c & 7;
      f16x8 va = *reinterpret_cast<const f16x8*>(w + (size_t)(by*128+row)*HH + kt*64 + o*8);
      f16x8 vb = *reinterpret_cast<const f16x8*>(x + (size_t)(bx*128+row)*HH + kt*64 + o*8);
      *reinterpret_cast<f16x8*>(&lA[row*LDAP + o*8]) = va;
      *reinterpret_cast<f16x8*>(&lB[row*LDAP + o*8]) = vb;
    }
    __syncthreads();
#pragma unroll
    for (int kk = 0; kk < 2; ++kk){
      f16x8 aF[4], bF[4];
#pragma unroll
      for (int mi=0;mi<4;mi++)
        aF[mi] = *reinterpret_cast<const f16x8*>(&lA[(wm*64+mi*16+(l&15))*LDAP + kk*32 + (l>>4)*8]);
#pragma unroll
      for (int ni=0;ni<4;ni++)
        bF[ni] = *reinterpret_cast<const f16x8*>(&lB[(wn*64+ni*16+(l&15))*LDAP + kk*32 + (l>>4)*8]);
#pragma unroll
      for (int mi=0;mi<4;mi++)
#pragma unroll
        for (int ni=0;ni<4;ni++)
          acc[mi][ni] = __builtin_amdgcn_mfma_f32_16x16x32_f16(aF[mi], bF[ni], acc[mi][ni], 0,0,0);
    }
    __syncthreads();
  }
  // epilogue: D m = (l>>4)*4+reg -> 4 consecutive wrows; n = l&15 -> xrow
#pragma unroll
  for (int mi=0;mi<4;mi++){
    int wrow0 = by*128 + wm*64 + mi*16 + (l>>4)*4;
    float4 bv = *reinterpret_cast<const float4*>(biasf + wrow0);
    int gate = wrow0 >> 9, j = wrow0 & 511, ksl = j >> 5, rp = gate*32 + (j&31);
#pragma unroll
    for (int ni=0;ni<4;ni++){
      int xrow = bx*128 + wn*64 + ni*16 + (l&15);
      int t = xrow >> 6, g = (xrow>>4)&3, bp = xrow & 15;
      size_t dst = ((((size_t)t*16 + ksl)*4 + g)*16 + bp)*96 + rp;
      union { u64 u; f16x4 h; } cv;
      cv.h = (f16x4){ (f16)(acc[mi][ni][0]+bv.x), (f16)(acc[mi][ni][1]+bv.y),
                      (f16)(acc[mi][ni][2]+bv.z), (f16)(acc[mi][ni][3]+bv.w) };
      *reinterpret_cast<u64*>(gi + dst) = cv.u;
    }
  }
}

// ---------------- persistent GRU scan: LDS-shared poll, B-frag staging, AGPR-resident W ----------------
// 32 WGs x 256 thr (4 waves). WG (g, c): group g (16 batches), c in 0..7. Wave w owns
// j-slice jsl = c*4+w (16 j, 48 W rows -> 192 regs PINNED IN AGPRS: "+a" — MFMA reads
// A from AGPR natively, AGPRs are outside the v0-255 VALU limit so no spill).
// h exchange: hh[t][g][jsl][b][16j], chunk = CHK f16 = 512 B: producer wave's 512 B
// contiguous; consumer wave polls 8 contiguous chunks (full lines) and stages into
// B-FRAGMENT LDS layout hbF[par][kt][lane][8] -> ds_read_b128 is bank-conflict-FREE
// (round-7 layout had 8-way conflicts on read: row stride 260 dwords ≡ 4 mod 32).
// Poll-the-data: hh poisoned 0xFF (finite h never makes f16 0xFFFF); u64 chunks
// all-or-nothing via single relaxed agent-atomic stores.
__global__ __launch_bounds__(256, 1) void k_scan(const f16* __restrict__ whh_h, const f16* __restrict__ gi,
                      const float* __restrict__ bhh, f16* __restrict__ hh){
  __shared__ f16 hbF[2][16][64][8];                 // [parity][kt][frag-lane][8 f16] = 32 KB
  const int bid = blockIdx.x;                       // 0..31
  const int g = bid & 3, c = bid >> 2;              // group, wg-in-group
  const int tid = threadIdx.x;
  const int w = tid >> 6, l = tid & 63;
  const int lm = l & 15, lh = l >> 4;
  const int jsl = c*4 + w;                          // 0..31: this wave's 16-j slice

  // persistent A-fragments: aW[gate][kt], W row = gate*512 + jsl*16 + lm, k = kt*32 + lh*8
  f16x8 aW[3][16];
#pragma unroll
  for (int gate = 0; gate < 3; ++gate){
    const f16* wr = whh_h + ((size_t)gate*512 + jsl*16 + lm)*HH + lh*8;
#pragma unroll
    for (int kt = 0; kt < 16; ++kt)
      aW[gate][kt] = *reinterpret_cast<const f16x8*>(wr + kt*32);
  }
  // pin into AGPRs: opaque (no remat) AND outside the 256-VGPR VALU window (no spill)
#pragma unroll
  for (int gate = 0; gate < 3; ++gate)
#pragma unroll
    for (int kt = 0; kt < 16; ++kt)
      asm volatile("" : "+a"(aW[gate][kt]));

  const int jglob = jsl*16 + lh*4;                  // first of 4 j this lane owns
  float4 bnv = *reinterpret_cast<const float4*>(bhh + 2*HH + jglob);   // b_hh n-gate
  float bna[4] = {bnv.x, bnv.y, bnv.z, bnv.w};
  const int ksl2 = jsl >> 1, jo = (jsl & 1)*16 + lh*4;     // gi addressing

  union U64H { u64 u; f16x4 h; };
  U64H cA[3], cB[3], cC[3], ho, hn;
  ho.u = 0ull;

  // ---- t = 0 peel: h_{-1}=0, no poll; prefetch gi(1)->cB, gi(2)->cC ----
  {
    const f16* g0 = gi + ((((size_t)0*16 + ksl2)*4 + g)*16 + lm)*96;
    cA[0].u = *reinterpret_cast<const u64*>(g0 + jo);
    cA[1].u = *reinterpret_cast<const u64*>(g0 + 32 + jo);
    cA[2].u = *reinterpret_cast<const u64*>(g0 + 64 + jo);
    const f16* g1 = gi + ((((size_t)1*16 + ksl2)*4 + g)*16 + lm)*96;
    cB[0].u = *reinterpret_cast<const u64*>(g1 + jo);
    cB[1].u = *reinterpret_cast<const u64*>(g1 + 32 + jo);
    cB[2].u = *reinterpret_cast<const u64*>(g1 + 64 + jo);
    const f16* g2 = gi + ((((size_t)2*16 + ksl2)*4 + g)*16 + lm)*96;
    cC[0].u = *reinterpret_cast<const u64*>(g2 + jo);
    cC[1].u = *reinterpret_cast<const u64*>(g2 + 32 + jo);
    cC[2].u = *reinterpret_cast<const u64*>(g2 + 64 + jo);
#pragma unroll
    for (int r = 0; r < 4; ++r){
      float rg = sigm((float)cA[0].h[r]);
      float zg = sigm((float)cA[1].h[r]);
      float ng = tanh_f((float)cA[2].h[r] + rg*bna[r]);
      hn.h[r] = (f16)((1.0f - zg)*ng);
    }
    ho.u = hn.u;
    __hip_atomic_store(reinterpret_cast<u64*>(hh + ((((size_t)0*4 + g)*32 + jsl)*CHK + lm*16 + lh*4)),
                       hn.u, __ATOMIC_RELAXED, __HIP_MEMORY_SCOPE_AGENT);
  }

  // BODY(T): poll 8 chunks of h(T-1) -> stage B-frag LDS; barrier; gi(T+2) prefetch; MFMA; gates; store h(T).
  // Stage mapping (chunk jj, lane l holds b=l>>2, j0=jj*16+(l&3)*4):
  //   kt = jj>>1, lh' = 2*(jj&1) + ((l&3)>>1), lane' = (l>>2) + 16*lh', off = (l&1)*4.
#define BODY(T, CUR, NXT2)                                                                           \
  {                                                                                                  \
    const int t_ = (T);                                                                              \
    const int par = t_ & 1;                                                                          \
    const u64* hsrc = reinterpret_cast<const u64*>(                                                  \
        hh + (((size_t)(t_-1)*4 + g)*32 + w*8)*CHK) + l;   /* chunk stride = CHK/4 = 64 u64 */       \
    u64 qq[8];                                                                                       \
    int ok;                                                                                          \
    do {                                                                                             \
      ok = 1;                                                                                        \
      _Pragma("unroll")                                                                              \
      for (int q = 0; q < 8; ++q){                                                                   \
        qq[q] = __hip_atomic_load(hsrc + (size_t)q*(CHK/4), __ATOMIC_RELAXED, __HIP_MEMORY_SCOPE_AGENT); \
        ok &= ((unsigned)qq[q] != 0xFFFFFFFFu);                                                      \
      }                                                                                              \
    } while (!__all(ok));                                                                            \
    _Pragma("unroll")                                                                                \
    for (int q = 0; q < 8; ++q){                                                                     \
      const int jj  = w*8 + q;                                                                       \
      const int ktq = jj >> 1;                                                                       \
      const int lhq = (jj & 1)*2 + ((l&3)>>1);                                                       \
      *reinterpret_cast<u64*>(&hbF[par][ktq][(l>>2) + 16*lhq][(l&1)*4]) = qq[q];                     \
    }                                                                                                \
    __syncthreads();                                                                                 \
    {   /* gi(t+2) prefetch: issued post-barrier, consumed 2 steps later */                          \
      const int tn_ = (t_+2 < TT) ? t_+2 : TT-1;                                                     \
      const f16* gn = gi + ((((size_t)tn_*16 + ksl2)*4 + g)*16 + lm)*96;                             \
      NXT2[0].u = *reinterpret_cast<const u64*>(gn + jo);                                            \
      NXT2[1].u = *reinterpret_cast<const u64*>(gn + 32 + jo);                                       \
      NXT2[2].u = *reinterpret_cast<const u64*>(gn + 64 + jo);                                       \
    }                                                                                                \
    f32x4 aR = (f32x4){0.f,0.f,0.f,0.f};                                                             \
    f32x4 aZ = (f32x4){0.f,0.f,0.f,0.f};                                                             \
    f32x4 aN = (f32x4){0.f,0.f,0.f,0.f};                                                             \
    _Pragma("unroll")                                                                                \
    for (int kt = 0; kt < 16; ++kt){                                                                 \
      f16x8 bF = *reinterpret_cast<const f16x8*>(&hbF[par][kt][l][0]);                               \
      aR = __builtin_amdgcn_mfma_f32_16x16x32_f16(aW[0][kt], bF, aR, 0,0,0);                         \
      aZ = __builtin_amdgcn_mfma_f32_16x16x32_f16(aW[1][kt], bF, aZ, 0,0,0);                         \
      aN = __builtin_amdgcn_mfma_f32_16x16x32_f16(aW[2][kt], bF, aN, 0,0,0);                         \
    }                                                                                                \
    _Pragma("unroll")                                                                                \
    for (int r = 0; r < 4; ++r){                                                                     \
      float rg = sigm((float)CUR[0].h[r] + aR[r]);                                                   \
      float zg = sigm((float)CUR[1].h[r] + aZ[r]);                                                   \
      float ng = tanh_f((float)CUR[2].h[r] + rg*(aN[r] + bna[r]));                                   \
      hn.h[r] = (f16)((1.0f - zg)*ng + zg*(float)ho.h[r]);                                           \
    }                                                                                                \
    ho.u = hn.u;                                                                                     \
    __hip_atomic_store(reinterpret_cast<u64*>(hh + ((((size_t)t_*4 + g)*32 + jsl)*CHK + lm*16 + lh*4)),\
                       hn.u, __ATOMIC_RELAXED, __HIP_MEMORY_SCOPE_AGENT);                            \
  }

  // t = 1..1023 in 341 triples, 3-buffer gi rotation
  for (int t = 1; t < TT; t += 3){
    BODY(t,   cB, cA)
    BODY(t+1, cC, cB)
    BODY(t+2, cA, cC)
  }
#undef BODY
}

// ---------------- rewards = sigmoid(h @ W_t + b_t) (chunked hh layout, stride CHK) ----------------
__global__ void k_reward(const f16* __restrict__ hh, const float* __restrict__ wt,
                         const float* __restrict__ bt, float* __restrict__ out){
  int wv = threadIdx.x >> 6, l = threadIdx.x & 63;
  int idx = blockIdx.x*4 + wv;          // idx = b*1024 + t (output order [B][T])
  int b = idx >> 10, t = idx & 1023;
  int g = b >> 4, bl = b & 15;
  // element j of h(b,t) lives at hh[((t*4+g)*32 + (j>>4))*CHK + bl*16 + (j&15)]
  const f16* hr = hh + (((size_t)t*4 + g)*32 + (l >> 1))*CHK + bl*16 + (l & 1)*8;
  f16x8 hv = *reinterpret_cast<const f16x8*>(hr);      // j = l*8 .. l*8+7
  float4 w0 = *reinterpret_cast<const float4*>(wt + l*8);
  float4 w1 = *reinterpret_cast<const float4*>(wt + l*8 + 4);
  float sum = (float)hv[0]*w0.x + (float)hv[1]*w0.y + (float)hv[2]*w0.z + (float)hv[3]*w0.w
            + (float)hv[4]*w1.x + (float)hv[5]*w1.y + (float)hv[6]*w1.z + (float)hv[7]*w1.w;
#pragma unroll
  for (int m=32;m>=1;m>>=1) sum += __shfl_xor(sum, m);
  if (l==0) out[idx] = sigm(sum + bt[0]);
}

extern "C" void kernel_launch(void* const* d_in, const int* in_sizes, int n_in,
                              void* d_out, int out_size, void* d_ws, size_t ws_size,
                              hipStream_t stream) {
  const float* s   = (const float*)d_in[0];
  const float* p   = (const float*)d_in[1];
  const float* wih = (const float*)d_in[2];
  const float* whh = (const float*)d_in[3];
  const float* bih = (const float*)d_in[4];
  const float* bhh = (const float*)d_in[5];
  const float* wt  = (const float*)d_in[6];
  const float* bt  = (const float*)d_in[7];
  float* out = (float*)d_out;

  char* ws = (char*)d_ws;
  size_t o = 0;
  auto take = [&](size_t bytes)->char*{ char* r = ws + o; o = (o + bytes + 255) & ~(size_t)255; return r; };
  f16*      x_h   = (f16*)   take((size_t)TT*BB*HH*2);       // 67 MB
  f16*      wih_h = (f16*)   take((size_t)G3*HH*2);
  f16*      whh_h = (f16*)   take((size_t)G3*HH*2);
  float*    biasf = (float*) take((size_t)G3*4);
  f16*      gi_s  = (f16*)   take((size_t)TT*BB*G3*2);       // 201 MB
  f16*      hh    = (f16*)   take((size_t)TT*BB*HH*2);       // 67 MB, chunked layout (CHK f16/chunk)
  (void)ws_size; (void)in_sizes; (void)n_in; (void)out_size;

  hipMemsetAsync(hh, 0xFF, (size_t)TT*BB*HH*2, stream);      // poison: poll-the-data sentinel
  k_prep  <<<3072, 256, 0, stream>>>(wih, whh, bih, bhh, wih_h, whh_h, biasf);
  k_buildx<<<TT*BB, 64, 0, stream>>>(s, p, x_h);
  k_gemm  <<<dim3(12, 512), 256, 0, stream>>>(x_h, wih_h, biasf, gi_s);
  k_scan  <<<32, 256, 0, stream>>>(whh_h, gi_s, bhh, hh);
  k_reward<<<TT*BB/4, 256, 0, stream>>>(hh, wt, bt, out);
}